// Round 6
// baseline (201.905 us; speedup 1.0000x reference)
//
#include <hip/hip_runtime.h>
#include <hip/hip_bf16.h>

// DenseAttention — reassociated (6.44 GF vs 155 GF direct), bf16 MFMA, 5 plain
// dispatches (round 6: round-4 structure minus the prep pass; cooperative
// launch from round 5 failed silently — reverted).
//   memset: zero G+Wt (4 MB)
//   gram:   G[b,q]  = X_bq^T X_bq      grid(4,8,8), split-K8, atomic
//   2a:     Tt[ba]  = (G @ C_aq)^T     grid(4,32), per-q, written transposed
//   2b:     Wt[ba]  = (Qw_a @ T)^T     grid(4,8,4), split-K4, atomic
//   out:    out     = X_ba @ Wt^T      grid(32,8)
// No prep: K-major f32 sources (x-columns for gram, comb for 2a) are scatter-
// staged straight into fragment-major LDS with on-the-fly f32->bf16 (stage_km);
// k-contiguous sources (x rows, qw, G, Tt, Wt) use the vector stager (stage_row,
// identical to round 4's verified float path).
// Fragment-major LDS: lane l's 16B frag chunk contiguous -> conflict-free
// ds_read_b128. MFMA layouts identical to round 4 (verified PASS).
// ws (12 MB): G 2MB | Wt 2MB | Tt 8MB.

typedef unsigned short u16;
using short8  = __attribute__((ext_vector_type(8))) short;
using floatx4 = __attribute__((ext_vector_type(4))) float;

__device__ inline u16 f2bf(float f) {               // RNE f32->bf16
    unsigned u = __float_as_uint(f);
    unsigned r = u + 0x7fffu + ((u >> 16) & 1u);
    return (u16)(r >> 16);
}

// Row-major source [128 m][64 k] (k-contiguous), f32 -> fragment-major LDS.
__device__ inline void stage_row(const float* __restrict__ src, long ld,
                                 u16* __restrict__ dst, int tid) {
#pragma unroll
    for (int it = 0; it < 8; ++it) {
        const int flat = (it * 256 + tid) * 4;
        const int kl = flat & 63, rl = flat >> 6;
        const float4 f = *(const float4*)&src[(long)rl * ld + kl];
        ushort4 v;
        v.x = f2bf(f.x); v.y = f2bf(f.y); v.z = f2bf(f.z); v.w = f2bf(f.w);
        const int chunk = ((kl >> 5) * 8 + (rl >> 4)) * 64 + ((kl >> 3) & 3) * 16 + (rl & 15);
        *(ushort4*)&dst[chunk * 8 + (kl & 7)] = v;
    }
}

// K-major source [64 k][128 m] (m-contiguous), f32 -> fragment-major LDS (scatter).
__device__ inline void stage_km(const float* __restrict__ src, long ld,
                                u16* __restrict__ dst, int tid) {
#pragma unroll
    for (int it = 0; it < 8; ++it) {
        const int flat = (it * 256 + tid) * 4;
        const int m = flat & 127, k = flat >> 7;
        const float4 f = *(const float4*)&src[(long)k * ld + m];
        // chunk for (m+e, k); m%4==0 and (m&15)<=12 so chunk increments by e
        const int cb = ((k >> 5) * 8 + (m >> 4)) * 64 + ((k & 31) >> 3) * 16 + (m & 15);
        const int j = k & 7;
        dst[(cb + 0) * 8 + j] = f2bf(f.x);
        dst[(cb + 1) * 8 + j] = f2bf(f.y);
        dst[(cb + 2) * 8 + j] = f2bf(f.z);
        dst[(cb + 3) * 8 + j] = f2bf(f.w);
    }
}

// C[m0+..128, n0+..128] (+)= A @ B^T_rows, K in 64-steps, 4 waves x 64x64 each.
// AKM/BKM: operand is K-major (scatter stager; pass src at [k][m-origin]).
// CT: write C[n][m]. ATOMIC: atomicAdd (split-K).
template <bool AKM, bool BKM, bool CT, bool ATOMIC>
__device__ inline void gemm_tile(const float* __restrict__ A, long lda,
                                 const float* __restrict__ B, long ldb,
                                 float* __restrict__ C, long ldc,
                                 int K, int m0, int n0) {
    __shared__ u16 As[8192];   // 2 ksteps x 8 mtiles x 64 lanes x 8 bf16 = 16 KB
    __shared__ u16 Bs[8192];
    const int tid = threadIdx.x, lane = tid & 63, w = tid >> 6;
    const int IA = (w & 1) * 4, JB = (w >> 1) * 4;
    floatx4 acc[4][4] = {};

    for (int k0 = 0; k0 < K; k0 += 64) {
        if (AKM) stage_km(A + (long)k0 * lda, lda, As, tid);
        else     stage_row(A + k0, lda, As, tid);
        if (BKM) stage_km(B + (long)k0 * ldb, ldb, Bs, tid);
        else     stage_row(B + k0, ldb, Bs, tid);
        __syncthreads();
#pragma unroll
        for (int s = 0; s < 2; ++s) {
            short8 af[4], bfr[4];
#pragma unroll
            for (int i = 0; i < 4; ++i)
                af[i] = *(const short8*)&As[((s * 8 + IA + i) * 64 + lane) * 8];
#pragma unroll
            for (int j = 0; j < 4; ++j)
                bfr[j] = *(const short8*)&Bs[((s * 8 + JB + j) * 64 + lane) * 8];
#pragma unroll
            for (int i = 0; i < 4; ++i)
#pragma unroll
                for (int j = 0; j < 4; ++j)
                    acc[i][j] = __builtin_amdgcn_mfma_f32_16x16x32_bf16(af[i], bfr[j], acc[i][j], 0, 0, 0);
        }
        __syncthreads();
    }
    const int rb = (lane >> 4) * 4, col = lane & 15;
#pragma unroll
    for (int i = 0; i < 4; ++i)
#pragma unroll
        for (int j = 0; j < 4; ++j)
#pragma unroll
            for (int r = 0; r < 4; ++r) {
                const int gm = m0 + IA * 16 + i * 16 + rb + r;
                const int gn = n0 + JB * 16 + j * 16 + col;
                float* p = CT ? &C[(long)gn * ldc + gm] : &C[(long)gm * ldc + gn];
                if (ATOMIC) atomicAdd(p, acc[i][j][r]); else *p = acc[i][j][r];
            }
}

// gram: G[bq][f][h] += sum_{u in split} x[b][u][q*256+f] * x[b][u][q*256+h]
__global__ __launch_bounds__(256) void k_gram(const float* __restrict__ x,
                                              float* __restrict__ G) {
    const int tile = blockIdx.x, bq = blockIdx.y, split = blockIdx.z;
    const int tm = tile >> 1, tn = tile & 1;
    const int b = bq >> 2, q = bq & 3;
    const float* base = x + (long)b * 2097152 + (long)split * 256 * 1024 + q * 256;
    gemm_tile<true, true, false, true>(base + tm * 128, 1024,
                                       base + tn * 128, 1024,
                                       G + (long)bq * 65536, 256,
                                       256, tm * 128, tn * 128);
}

// 2a: Tt[ba][g][q*256+f] = sum_h G[bq][f][h] * comb[a][q*256+h][g]
__global__ __launch_bounds__(256) void k_2a(const float* __restrict__ G,
                                            const float* __restrict__ comb,
                                            float* __restrict__ Tt) {
    const int tile = blockIdx.x, i = blockIdx.y;     // i = ba*4+q
    const int tm = tile >> 1, tn = tile & 1;
    const int q = i & 3, ba = i >> 2, b = ba >> 2, a = ba & 3;
    gemm_tile<false, true, true, false>(
        G + (long)(b * 4 + q) * 65536 + (long)tm * 128 * 256, 256,
        comb + (long)a * 262144 + (long)q * 256 * 256 + tn * 128, 256,
        Tt + (long)ba * 262144, 1024,
        256, q * 256 + tm * 128, tn * 128);
}

// 2b: Wt[ba][g][e] += sum_{k in split} qw[a][e][k] * Tt[ba][g][k]
__global__ __launch_bounds__(256) void k_2b(const float* __restrict__ qw,
                                            const float* __restrict__ Tt,
                                            float* __restrict__ Wt) {
    const int tile = blockIdx.x, ba = blockIdx.y, split = blockIdx.z;
    const int tm = tile >> 1, tn = tile & 1;
    const int a = ba & 3;
    gemm_tile<false, false, true, true>(
        qw + (long)a * 262144 + (long)tm * 128 * 1024 + split * 256, 1024,
        Tt + (long)ba * 262144 + (long)tn * 128 * 1024 + split * 256, 1024,
        Wt + (long)ba * 65536, 256,
        256, tm * 128, tn * 128);
}

// out: out[b][t][a*256+g] = sum_e x[b][t][a*256+e] * Wt[ba][g][e]
__global__ __launch_bounds__(256) void k_3(const float* __restrict__ x,
                                           const float* __restrict__ Wt,
                                           float* __restrict__ out) {
    const int tl = blockIdx.x, ba = blockIdx.y;      // tl: tm 0..15, tn 0..1
    const int tm = tl >> 1, tn = tl & 1;
    const int b = ba >> 2, a = ba & 3;
    gemm_tile<false, false, false, false>(
        x + (long)b * 2097152 + (long)tm * 128 * 1024 + a * 256, 1024,
        Wt + (long)ba * 65536 + (long)tn * 128 * 256, 256,
        out + (long)b * 2097152 + a * 256, 1024,
        256, tm * 128, tn * 128);
}

extern "C" void kernel_launch(void* const* d_in, const int* in_sizes, int n_in,
                              void* d_out, int out_size, void* d_ws, size_t ws_size,
                              hipStream_t stream) {
    const float* x    = (const float*)d_in[0];   // [2,2048,1024]
    const float* qw   = (const float*)d_in[1];   // [4,256,1024]
    const float* comb = (const float*)d_in[2];   // [4,1024,256]
    float* out = (float*)d_out;

    float* G  = (float*)d_ws;                    // 2 MB [8][256x256]
    float* Wt = G + 8 * 65536;                   // 2 MB [8][256x256] (W^T)
    float* Tt = Wt + 8 * 65536;                  // 8 MB [8][256][1024] (T^T)

    hipMemsetAsync(d_ws, 0, 4u << 20, stream);   // zero G + Wt (atomic accumulators)
    k_gram<<<dim3(4, 8, 8), 256, 0, stream>>>(x, G);
    k_2a  <<<dim3(4, 32),   256, 0, stream>>>(G, comb, Tt);
    k_2b  <<<dim3(4, 8, 4), 256, 0, stream>>>(qw, Tt, Wt);
    k_3   <<<dim3(32, 8),   256, 0, stream>>>(x, Wt, out);
}

// Round 7
// 141.762 us; speedup vs baseline: 1.4243x; 1.4243x over previous
//
#include <hip/hip_runtime.h>
#include <hip/hip_bf16.h>

// DenseAttention — reassociated (6.44 GF vs 155 GF direct), bf16 MFMA.
// Round 7: kill ALL transposed stores (round-6 counters: k_2b 53us from
// CT+atomic scatter = 64 cache lines per atomic wave-instr) by computing each
// stage's TRANSPOSED product natively with k-contiguous operands:
//   prep:  xb=bf16(x), xt=bf16(x^T), qb=bf16(qw), cb[a][g][k]=bf16(comb[a][k][g])
//          + zero G,Wt (folds memset dispatch)
//   gram:  G[bq][f][h] += xt_f . xt_h      grid(4,8,8) split-K8, atomic COALESCED
//   2a:    Tt[ba][g][qf] = cb_g . G_f      grid(4,32)   plain COALESCED
//   2b:    Wt[ba][g][e] += Tt_g . qb_e     grid(4,8,4) split-K4, atomic COALESCED
//   out:   out[t][ag]   = xb_t . Wt_g      grid(32,8)   plain COALESCED
// All LDS staging is the round-4-verified vector fragment-major path
// (conflict-free ds_read_b128 fragments); no scatter stager, no CT epilogue.
// ws (32 MB): G 2 | Wt 2 | Tt 8 | xb 8 | xt 8 | qb 2 | cb 2.

typedef unsigned short u16;
using short8  = __attribute__((ext_vector_type(8))) short;
using floatx4 = __attribute__((ext_vector_type(4))) float;

__device__ inline u16 f2bf(float f) {               // RNE f32->bf16
    unsigned u = __float_as_uint(f);
    unsigned r = u + 0x7fffu + ((u >> 16) & 1u);
    return (u16)(r >> 16);
}

// Row-major source [128 m][64 k] (k-contiguous) -> fragment-major LDS.
// f32 sources convert on the fly; u16 sources copy.
template <typename T>
__device__ inline void stage_row(const T* __restrict__ src, long ld,
                                 u16* __restrict__ dst, int tid) {
#pragma unroll
    for (int it = 0; it < 8; ++it) {
        const int flat = (it * 256 + tid) * 4;
        const int kl = flat & 63, rl = flat >> 6;
        ushort4 v;
        if (sizeof(T) == 4) {
            const float4 f = *(const float4*)&((const float*)src)[(long)rl * ld + kl];
            v.x = f2bf(f.x); v.y = f2bf(f.y); v.z = f2bf(f.z); v.w = f2bf(f.w);
        } else {
            v = *(const ushort4*)&((const u16*)src)[(long)rl * ld + kl];
        }
        const int chunk = ((kl >> 5) * 8 + (rl >> 4)) * 64 + ((kl >> 3) & 3) * 16 + (rl & 15);
        *(ushort4*)&dst[chunk * 8 + (kl & 7)] = v;
    }
}

// C[m0+..128, n0+..128] (+)= A . B^T  (A:[128 m][K], B:[128 n][K], both row-major
// k-contiguous, pointers pre-offset to their tile). Stores coalesced (lane->gn).
template <typename TA, typename TB, bool ATOMIC>
__device__ inline void gemm_tile(const TA* __restrict__ A, long lda,
                                 const TB* __restrict__ B, long ldb,
                                 float* __restrict__ C, long ldc,
                                 int K, int m0, int n0) {
    __shared__ u16 As[8192];   // 16 KB: 2 ksteps x 8 mtiles x 64 lanes x 8 bf16
    __shared__ u16 Bs[8192];
    const int tid = threadIdx.x, lane = tid & 63, w = tid >> 6;
    const int IA = (w & 1) * 4, JB = (w >> 1) * 4;
    floatx4 acc[4][4] = {};

    for (int k0 = 0; k0 < K; k0 += 64) {
        stage_row(A + k0, lda, As, tid);
        stage_row(B + k0, ldb, Bs, tid);
        __syncthreads();
#pragma unroll
        for (int s = 0; s < 2; ++s) {
            short8 af[4], bfr[4];
#pragma unroll
            for (int i = 0; i < 4; ++i)
                af[i] = *(const short8*)&As[((s * 8 + IA + i) * 64 + lane) * 8];
#pragma unroll
            for (int j = 0; j < 4; ++j)
                bfr[j] = *(const short8*)&Bs[((s * 8 + JB + j) * 64 + lane) * 8];
#pragma unroll
            for (int i = 0; i < 4; ++i)
#pragma unroll
                for (int j = 0; j < 4; ++j)
                    acc[i][j] = __builtin_amdgcn_mfma_f32_16x16x32_bf16(af[i], bfr[j], acc[i][j], 0, 0, 0);
        }
        __syncthreads();
    }
    const int rb = (lane >> 4) * 4, col = lane & 15;
#pragma unroll
    for (int i = 0; i < 4; ++i)
#pragma unroll
        for (int j = 0; j < 4; ++j)
#pragma unroll
            for (int r = 0; r < 4; ++r) {
                const int gm = m0 + IA * 16 + i * 16 + rb + r;
                const int gn = n0 + JB * 16 + j * 16 + col;
                float* p = &C[(long)gm * ldc + gn];
                if (ATOMIC) atomicAdd(p, acc[i][j][r]); else *p = acc[i][j][r];
            }
}

// 64x64 f32 tile transpose src[r0+..][c0+..] -> bf16 dst[c0+..][r0+..]
// (round-4-verified). Whole block participates.
__device__ inline void transpose64(const float* __restrict__ src, long lds_,
                                   int r0, int c0,
                                   u16* __restrict__ dst, long ldd,
                                   float (*tile)[65], int t) {
#pragma unroll
    for (int it = 0; it < 4; ++it) {
        const int row = (t >> 4) + it * 16, cq = (t & 15) * 4;
        *(float4*)&tile[row][cq] = *(const float4*)&src[(long)(r0 + row) * lds_ + c0 + cq];
    }
    __syncthreads();
#pragma unroll
    for (int it = 0; it < 4; ++it) {
        const int cl = (t >> 4) + it * 16, rq = (t & 15) * 4;
        ushort4 v;
        v.x = f2bf(tile[rq + 0][cl]); v.y = f2bf(tile[rq + 1][cl]);
        v.z = f2bf(tile[rq + 2][cl]); v.w = f2bf(tile[rq + 3][cl]);
        *(ushort4*)&dst[(long)(c0 + cl) * ldd + r0 + rq] = v;
    }
}

__global__ __launch_bounds__(256) void k_prep(const float* __restrict__ x,
                                              const float* __restrict__ qw,
                                              const float* __restrict__ comb,
                                              u16* __restrict__ xb,
                                              u16* __restrict__ xt,
                                              u16* __restrict__ qb,
                                              u16* __restrict__ cb,
                                              float* __restrict__ GZ) {
    __shared__ float tile[64][65];
    const int bid = blockIdx.x, t = threadIdx.x;
    if (bid < 1024) {                 // x: xb (row copy) + xt (transpose)
        const int b = bid >> 9, local = bid & 511;
        const int u0 = (local & 31) * 64, f0 = (local >> 5) * 64;
        const float* src = x + (long)b * 2097152;
#pragma unroll
        for (int it = 0; it < 4; ++it) {
            const int row = (t >> 4) + it * 16, cq = (t & 15) * 4;
            const float4 f = *(const float4*)&src[(long)(u0 + row) * 1024 + f0 + cq];
            *(float4*)&tile[row][cq] = f;
            ushort4 v;
            v.x = f2bf(f.x); v.y = f2bf(f.y); v.z = f2bf(f.z); v.w = f2bf(f.w);
            *(ushort4*)&xb[(long)b * 2097152 + (long)(u0 + row) * 1024 + f0 + cq] = v;
        }
        __syncthreads();
#pragma unroll
        for (int it = 0; it < 4; ++it) {
            const int cl = (t >> 4) + it * 16, rq = (t & 15) * 4;
            ushort4 v;
            v.x = f2bf(tile[rq + 0][cl]); v.y = f2bf(tile[rq + 1][cl]);
            v.z = f2bf(tile[rq + 2][cl]); v.w = f2bf(tile[rq + 3][cl]);
            *(ushort4*)&xt[(long)b * 2097152 + (long)(f0 + cl) * 2048 + u0 + rq] = v;
        }
    } else if (bid < 1280) {          // qw -> qb (straight convert, 4096 f32/block)
        const long base = (long)(bid - 1024) * 4096;
#pragma unroll
        for (int it = 0; it < 4; ++it) {
            const long off = base + (it * 256 + t) * 4;
            const float4 f = *(const float4*)&qw[off];
            ushort4 v;
            v.x = f2bf(f.x); v.y = f2bf(f.y); v.z = f2bf(f.z); v.w = f2bf(f.w);
            *(ushort4*)&qb[off] = v;
        }
    } else if (bid < 1536) {          // comb[a][k][g] -> cb[a][g][k]
        const int idx = bid - 1280, a = idx >> 6, local = idx & 63;
        const int k0 = (local & 15) * 64, g0 = (local >> 4) * 64;
        transpose64(comb + (long)a * 262144, 256, k0, g0,
                    cb + (long)a * 262144, 1024, tile, t);
    } else {                          // zero G + Wt (4 MB contiguous at GZ)
        float4 zero = {0.f, 0.f, 0.f, 0.f};
        float4* z = (float4*)GZ;
#pragma unroll
        for (int it = 0; it < 16; ++it)
            z[(long)(bid - 1536) * 4096 + it * 256 + t] = zero;
    }
}

// gram: G[bq][f][h] += sum_{u in split} xt[b][qf][u] * xt[b][qh][u]
__global__ __launch_bounds__(256) void k_gram(const u16* __restrict__ xt,
                                              float* __restrict__ G) {
    const int tile = blockIdx.x, bq = blockIdx.y, split = blockIdx.z;
    const int tm = tile >> 1, tn = tile & 1;
    const int b = bq >> 2, q = bq & 3;
    const u16* base = xt + (long)b * 2097152 + (long)q * 256 * 2048 + split * 256;
    gemm_tile<u16, u16, true>(base + (long)tm * 128 * 2048, 2048,
                              base + (long)tn * 128 * 2048, 2048,
                              G + (long)bq * 65536, 256,
                              256, tm * 128, tn * 128);
}

// 2a: Tt[ba][g][q*256+f] = sum_h cb[a][g][q*256+h] * G[bq][f][h]
__global__ __launch_bounds__(256) void k_2a(const u16* __restrict__ cb,
                                            const float* __restrict__ G,
                                            float* __restrict__ Tt) {
    const int tile = blockIdx.x, i = blockIdx.y;     // i = ba*4+q
    const int tm = tile >> 1, tn = tile & 1;
    const int q = i & 3, ba = i >> 2, b = ba >> 2, a = ba & 3;
    gemm_tile<u16, float, false>(
        cb + (long)a * 262144 + (long)tm * 128 * 1024 + q * 256, 1024,
        G + (long)(b * 4 + q) * 65536 + (long)tn * 128 * 256, 256,
        Tt + (long)ba * 262144, 1024,
        256, tm * 128, q * 256 + tn * 128);
}

// 2b: Wt[ba][g][e] += sum_{k in split} Tt[ba][g][k] * qb[a][e][k]
__global__ __launch_bounds__(256) void k_2b(const float* __restrict__ Tt,
                                            const u16* __restrict__ qb,
                                            float* __restrict__ Wt) {
    const int tile = blockIdx.x, ba = blockIdx.y, split = blockIdx.z;
    const int tm = tile >> 1, tn = tile & 1;
    const int a = ba & 3;
    gemm_tile<float, u16, true>(
        Tt + (long)ba * 262144 + (long)tm * 128 * 1024 + split * 256, 1024,
        qb + (long)a * 262144 + (long)tn * 128 * 1024 + split * 256, 1024,
        Wt + (long)ba * 65536, 256,
        256, tm * 128, tn * 128);
}

// out: out[b][t][a*256+g] = sum_e xb[b][t][a*256+e] * Wt[ba][g][e]
__global__ __launch_bounds__(256) void k_3(const u16* __restrict__ xb,
                                           const float* __restrict__ Wt,
                                           float* __restrict__ out) {
    const int tl = blockIdx.x, ba = blockIdx.y;      // tl: tm 0..15, tn 0..1
    const int tm = tl >> 1, tn = tl & 1;
    const int b = ba >> 2, a = ba & 3;
    gemm_tile<u16, float, false>(
        xb + (long)b * 2097152 + (long)tm * 128 * 1024 + a * 256, 1024,
        Wt + (long)ba * 65536 + (long)tn * 128 * 256, 256,
        out + (long)b * 2097152 + a * 256, 1024,
        256, tm * 128, tn * 128);
}

extern "C" void kernel_launch(void* const* d_in, const int* in_sizes, int n_in,
                              void* d_out, int out_size, void* d_ws, size_t ws_size,
                              hipStream_t stream) {
    const float* x    = (const float*)d_in[0];   // [2,2048,1024]
    const float* qw   = (const float*)d_in[1];   // [4,256,1024]
    const float* comb = (const float*)d_in[2];   // [4,1024,256]
    float* out = (float*)d_out;

    char* ws = (char*)d_ws;
    float* G  = (float*)(ws);                    // 2 MB [8][256x256] (G,Wt contiguous for zeroing)
    float* Wt = (float*)(ws + (2u << 20));       // 2 MB [8][256][256]  Wt[g][e]
    float* Tt = (float*)(ws + (4u << 20));       // 8 MB [8][256][1024] Tt[g][qf]
    u16* xb   = (u16*)  (ws + (12u << 20));      // 8 MB [2][2048][1024]
    u16* xt   = (u16*)  (ws + (20u << 20));      // 8 MB [2][1024][2048]
    u16* qb   = (u16*)  (ws + (28u << 20));      // 2 MB [4][256][1024]
    u16* cb   = (u16*)  (ws + (30u << 20));      // 2 MB [4][256][1024]

    k_prep<<<1600, 256, 0, stream>>>(x, qw, comb, xb, xt, qb, cb, G);
    k_gram<<<dim3(4, 8, 8), 256, 0, stream>>>(xt, G);
    k_2a  <<<dim3(4, 32),   256, 0, stream>>>(cb, G, Tt);
    k_2b  <<<dim3(4, 8, 4), 256, 0, stream>>>(Tt, qb, Wt);
    k_3   <<<dim3(32, 8),   256, 0, stream>>>(xb, Wt, out);
}